// Round 1
// baseline (658.613 us; speedup 1.0000x reference)
//
#include <hip/hip_runtime.h>

// MoE MLP (B=2,T=2048,H=1024,E=8,F=4096,K=2), fp32 in/out.
// Strategy: route -> group tokens by expert -> grouped bf16-MFMA GEMMs
// (only the 2 selected experts per token) -> weighted combine.
// Out: mixed [4096*1024] fp32, aux_loss, statement_loss(=0).

typedef unsigned short ushort_t;
typedef __attribute__((ext_vector_type(4))) unsigned int u32x4;
typedef __attribute__((ext_vector_type(4))) unsigned short u16x4;
typedef __attribute__((ext_vector_type(4))) float f32x4;
typedef __attribute__((ext_vector_type(8))) __bf16 bf16x8;

#define NTOK 4096   // B*T
#define HD   1024
#define FD   4096
#define NE   8
#define NKTOT 8192  // NTOK * TOP_K

__device__ __forceinline__ ushort_t f2bf(float f) {
  unsigned u = __builtin_bit_cast(unsigned, f);
  u += 0x7fffu + ((u >> 16) & 1u);   // RNE
  return (ushort_t)(u >> 16);
}

__device__ __forceinline__ bf16x8 frag_ld(const void* p) {
  u32x4 v = *reinterpret_cast<const u32x4*>(p);
  return __builtin_bit_cast(bf16x8, v);
}

#define GLOAD16(g, l) __builtin_amdgcn_global_load_lds(                         \
    (const __attribute__((address_space(1))) unsigned int*)(g),                 \
    (__attribute__((address_space(3))) unsigned int*)(l), 16, 0, 0)

// ---------------------------------------------------------------- init
__global__ void init_k(int* counts) {
  if (threadIdx.x < NE) counts[threadIdx.x] = 0;
}

// ------------------------------------------------------- x fp32->bf16
__global__ void convx_k(const float* __restrict__ src, ushort_t* __restrict__ dst) {
  const size_t i = ((size_t)blockIdx.x * 256 + threadIdx.x) * 4;
  const f32x4 v = *reinterpret_cast<const f32x4*>(src + i);
  u16x4 o;
  o.x = f2bf(v.x); o.y = f2bf(v.y); o.z = f2bf(v.z); o.w = f2bf(v.w);
  *reinterpret_cast<u16x4*>(dst + i) = o;
}

// --------------------------- transpose+convert: src[z][R][C] -> dst[z][C][R]
__global__ void tconv_k(const float* __restrict__ src, ushort_t* __restrict__ dst,
                        int R, int C) {
  __shared__ float tile[64][65];
  const size_t zb = (size_t)blockIdx.z * R * C;
  const float* s = src + zb;
  ushort_t* d = dst + zb;
  const int r0 = blockIdx.y * 64, c0 = blockIdx.x * 64;
  const int tid = threadIdx.x;
#pragma unroll
  for (int i = 0; i < 16; ++i) {
    const int idx = tid + i * 256;
    const int r = idx >> 6, c = idx & 63;
    tile[r][c] = s[(size_t)(r0 + r) * C + (c0 + c)];
  }
  __syncthreads();
#pragma unroll
  for (int i = 0; i < 16; ++i) {
    const int idx = tid + i * 256;
    const int cc = idx >> 6, rr = idx & 63;
    d[(size_t)(c0 + cc) * R + (r0 + rr)] = f2bf(tile[rr][cc]);
  }
}

// ---------------------------------------------------------------- router
__global__ void router_k(const float* __restrict__ x, const float* __restrict__ rw,
                         float* __restrict__ tokP, int* __restrict__ counts,
                         int* __restrict__ tk_e, int* __restrict__ tk_s,
                         float* __restrict__ tk_w) {
  const int w = threadIdx.x >> 6, l = threadIdx.x & 63;
  const int t = blockIdx.x * 4 + w;
  const float* xr = x + (size_t)t * HD;
  float acc[NE];
#pragma unroll
  for (int e = 0; e < NE; ++e) acc[e] = 0.f;
  for (int it = 0; it < HD / 64; ++it) {
    const int h = l + it * 64;
    const float xv = xr[h];
#pragma unroll
    for (int e = 0; e < NE; ++e) acc[e] = fmaf(xv, rw[e * HD + h], acc[e]);
  }
#pragma unroll
  for (int e = 0; e < NE; ++e) {
#pragma unroll
    for (int s = 32; s > 0; s >>= 1) acc[e] += __shfl_xor(acc[e], s, 64);
  }
  // full softmax (for aux loss P): every lane has all logits
  float m = acc[0];
#pragma unroll
  for (int e = 1; e < NE; ++e) m = fmaxf(m, acc[e]);
  float ssum = 0.f;
  float p[NE];
#pragma unroll
  for (int e = 0; e < NE; ++e) { p[e] = expf(acc[e] - m); ssum += p[e]; }
  const float inv = 1.f / ssum;
  if (l < NE) tokP[(size_t)t * NE + l] = p[l] * inv;

  if (l == 0) {
    int i0 = 0; float v0 = acc[0];
#pragma unroll
    for (int e = 1; e < NE; ++e) if (acc[e] > v0) { v0 = acc[e]; i0 = e; }
    int i1 = -1; float v1 = -3.4e38f;
#pragma unroll
    for (int e = 0; e < NE; ++e) if (e != i0 && acc[e] > v1) { v1 = acc[e]; i1 = e; }
    const float w0 = 1.f / (1.f + expf(v1 - v0));  // softmax([v0,v1])[0], stable
    const int s0 = atomicAdd(&counts[i0], 1);
    const int s1 = atomicAdd(&counts[i1], 1);
    tk_e[2 * t] = i0;     tk_s[2 * t] = s0;     tk_w[2 * t] = w0;
    tk_e[2 * t + 1] = i1; tk_s[2 * t + 1] = s1; tk_w[2 * t + 1] = 1.f - w0;
  }
}

// ------------------------------------------- offsets + aux loss + tail out
__global__ void finalize_k(const float* __restrict__ tokP, const int* __restrict__ counts,
                           int* __restrict__ offsets, float* __restrict__ out_tail) {
  __shared__ float red[64];
  const int tid = threadIdx.x;          // 64 threads
  const int e = tid & 7, part = tid >> 3;
  float s = 0.f;
  for (int j = part; j < NTOK; j += 8) s += tokP[(size_t)j * NE + e];
  red[tid] = s;
  __syncthreads();
  if (tid == 0) {
    int cnt[NE]; int off = 0; float aux = 0.f;
    for (int q = 0; q < NE; ++q) cnt[q] = counts[q];
    for (int q = 0; q < NE; ++q) { offsets[q] = off; off += cnt[q]; }
    for (int q = 0; q < NE; ++q) {
      float P = 0.f;
      for (int pp = 0; pp < 8; ++pp) P += red[pp * 8 + q];
      P *= (1.f / NTOK);
      aux += ((float)cnt[q] / (float)NKTOT) * P;
    }
    out_tail[0] = (float)NE * aux;  // aux_loss
    out_tail[1] = 0.f;              // statement_loss
  }
}

// ---------------------------------------------------------------- slots
__global__ void build_slots_k(const int* __restrict__ tk_e, const int* __restrict__ tk_s,
                              const int* __restrict__ offsets, int* __restrict__ slot_token) {
  const int i = blockIdx.x * 256 + threadIdx.x;  // < NKTOT
  const int e = tk_e[i];
  slot_token[offsets[e] + tk_s[i]] = i >> 1;
}

// ------------------------------------------------ grouped GEMM (bf16 MFMA)
// G1: mid[pos][FD] = gelu(X[tok] @ W1T[e]^T + b1[e])    A=Xbf (gathered), K=HD, N=FD
// G2: ybuf[pos][HD] = mid[pos] @ W2T[e]^T + b2[e]       A=mid (contig),   K=FD, N=HD
template <bool G1>
__global__ __launch_bounds__(256) void moe_gemm(
    const ushort_t* __restrict__ A, const ushort_t* __restrict__ B,
    const float* __restrict__ bias,
    const int* __restrict__ counts, const int* __restrict__ offsets,
    const int* __restrict__ slot_token,
    ushort_t* __restrict__ midout, float* __restrict__ yout) {
  constexpr int KD = G1 ? HD : FD;
  constexpr int ND = G1 ? FD : HD;
  const int e = blockIdx.z;
  const int cnt = counts[e];
  const int ty = blockIdx.y;
  if (ty * 128 >= cnt) return;
  const int off = offsets[e];
  const int rows_rem = cnt - ty * 128;      // valid rows in this tile
  const int pos0 = off + ty * 128;
  const int n0 = blockIdx.x * 128;

  __shared__ __align__(16) ushort_t As[128 * 64];
  __shared__ __align__(16) ushort_t Bs[128 * 64];

  const int tid = threadIdx.x;
  const int w = tid >> 6, l = tid & 63;
  // staging source byte-in-row, pre-swizzled so linear LDS == swizzled layout:
  // LDS(row, b) = G(row, b ^ ((row&7)<<4)); staged row&7 == l>>3.
  const int swz = 16 * ((l & 7) ^ (l >> 3));

  const char* aptr[4];
  const char* bptr[4];
#pragma unroll
  for (int j = 0; j < 4; ++j) {
    const int ra = w * 32 + j * 8 + (l >> 3);
    int pos = pos0 + ra;
    if (pos > NKTOT - 1) pos = NKTOT - 1;   // clamp (masked at store)
    const size_t arow = G1 ? (size_t)slot_token[pos] : (size_t)pos;
    aptr[j] = (const char*)A + arow * KD * 2 + swz;
    const int rb = n0 + w * 32 + j * 8 + (l >> 3);
    bptr[j] = (const char*)B + ((size_t)e * ND + rb) * KD * 2 + swz;
  }

  f32x4 acc[4][4] = {};
  const int wr = w >> 1, wc = w & 1;
  char* AsB = (char*)As;
  char* BsB = (char*)Bs;

  for (int ks = 0; ks < KD / 64; ++ks) {
#pragma unroll
    for (int j = 0; j < 4; ++j) {
      GLOAD16(aptr[j], AsB + w * 4096 + j * 1024);
      aptr[j] += 128;
    }
#pragma unroll
    for (int j = 0; j < 4; ++j) {
      GLOAD16(bptr[j], BsB + w * 4096 + j * 1024);
      bptr[j] += 128;
    }
    __syncthreads();   // drains vmcnt before barrier (compiler-enforced)
#pragma unroll
    for (int kk = 0; kk < 2; ++kk) {
      const int kb = kk * 64 + (l >> 4) * 16;   // byte offset of k-chunk in row
      const int sw = (l & 7) << 4;              // == (row&7)<<4 for our rows
      bf16x8 afr[4], bfr[4];
#pragma unroll
      for (int mm = 0; mm < 4; ++mm) {
        const int row = wr * 64 + mm * 16 + (l & 15);
        afr[mm] = frag_ld(AsB + row * 128 + (kb ^ sw));
      }
#pragma unroll
      for (int nn = 0; nn < 4; ++nn) {
        const int row = wc * 64 + nn * 16 + (l & 15);
        bfr[nn] = frag_ld(BsB + row * 128 + (kb ^ sw));
      }
#pragma unroll
      for (int mm = 0; mm < 4; ++mm)
#pragma unroll
        for (int nn = 0; nn < 4; ++nn)
          acc[mm][nn] = __builtin_amdgcn_mfma_f32_16x16x32_bf16(
              afr[mm], bfr[nn], acc[mm][nn], 0, 0, 0);
    }
    __syncthreads();
  }

  // epilogue: C/D layout col = l&15, row = 4*(l>>4) + j
  const int lr = (l >> 4) * 4, lc = l & 15;
#pragma unroll
  for (int nn = 0; nn < 4; ++nn) {
    const int col = n0 + wc * 64 + nn * 16 + lc;
    const float bv = bias[(size_t)e * ND + col];
#pragma unroll
    for (int mm = 0; mm < 4; ++mm) {
      const int rbase = wr * 64 + mm * 16 + lr;
#pragma unroll
      for (int j = 0; j < 4; ++j) {
        const int row = rbase + j;
        if (row < rows_rem) {
          float v = acc[mm][nn][j] + bv;
          if (G1) {
            v = 0.5f * v * (1.0f + erff(v * 0.70710678118654752f));  // exact gelu
            midout[(size_t)(pos0 + row) * FD + col] = f2bf(v);
          } else {
            yout[(size_t)(pos0 + row) * HD + col] = v;
          }
        }
      }
    }
  }
}

// ---------------------------------------------------------------- combine
__global__ void combine_k(const float* __restrict__ ybuf, const int* __restrict__ tk_e,
                          const int* __restrict__ tk_s, const float* __restrict__ tk_w,
                          const int* __restrict__ offsets, float* __restrict__ out) {
  const int t = blockIdx.x;
  const int e0 = tk_e[2 * t], e1 = tk_e[2 * t + 1];
  const size_t p0 = (size_t)offsets[e0] + tk_s[2 * t];
  const size_t p1 = (size_t)offsets[e1] + tk_s[2 * t + 1];
  const float w0 = tk_w[2 * t], w1v = tk_w[2 * t + 1];
  const int h = threadIdx.x * 4;
  const f32x4 y0 = *reinterpret_cast<const f32x4*>(ybuf + p0 * HD + h);
  const f32x4 y1 = *reinterpret_cast<const f32x4*>(ybuf + p1 * HD + h);
  f32x4 o = y0 * w0 + y1 * w1v;
  *reinterpret_cast<f32x4*>(out + (size_t)t * HD + h) = o;
}

// ---------------------------------------------------------------- launch
extern "C" void kernel_launch(void* const* d_in, const int* in_sizes, int n_in,
                              void* d_out, int out_size, void* d_ws, size_t ws_size,
                              hipStream_t stream) {
  const float* x  = (const float*)d_in[0];
  const float* rw = (const float*)d_in[1];
  const float* w1 = (const float*)d_in[2];
  const float* b1 = (const float*)d_in[3];
  const float* w2 = (const float*)d_in[4];
  const float* b2 = (const float*)d_in[5];
  float* out = (float*)d_out;

  char* ws = (char*)d_ws;
  // layout (bytes):
  ushort_t* Xbf  = (ushort_t*)(ws + 0);            //  8,388,608
  ushort_t* W1T  = (ushort_t*)(ws + 8388608);      // 67,108,864  [E][F][H]
  ushort_t* W2T  = (ushort_t*)(ws + 75497472);     // 67,108,864  [E][H][F]
  ushort_t* midb = (ushort_t*)(ws + 142606336);    // 67,108,864  [NKTOT][F]
  float*    ybuf = (float*)(ws + 8388608);         // 33,554,432  aliases W1T (dead after G1)
  char* sm = ws + 209715200;
  int*   counts  = (int*)(sm);
  int*   offsets = (int*)(sm + 64);
  float* tokP    = (float*)(sm + 128);             // [NTOK][NE] = 131072 B
  int*   tk_e    = (int*)(sm + 128 + 131072);
  int*   tk_s    = (int*)(sm + 128 + 131072 + 32768);
  float* tk_w    = (float*)(sm + 128 + 131072 + 65536);
  int*   slot_token = (int*)(sm + 128 + 131072 + 98304);

  init_k<<<1, 64, 0, stream>>>(counts);
  convx_k<<<4096, 256, 0, stream>>>(x, Xbf);
  tconv_k<<<dim3(64, 16, 8), 256, 0, stream>>>(w1, W1T, HD, FD);  // [H][F]->[F][H]
  tconv_k<<<dim3(16, 64, 8), 256, 0, stream>>>(w2, W2T, FD, HD);  // [F][H]->[H][F]
  router_k<<<1024, 256, 0, stream>>>(x, rw, tokP, counts, tk_e, tk_s, tk_w);
  finalize_k<<<1, 64, 0, stream>>>(tokP, counts, offsets, out + (size_t)NTOK * HD);
  build_slots_k<<<32, 256, 0, stream>>>(tk_e, tk_s, offsets, slot_token);
  moe_gemm<true><<<dim3(FD / 128, 32, NE), 256, 0, stream>>>(
      Xbf, W1T, b1, counts, offsets, slot_token, midb, (float*)nullptr);
  moe_gemm<false><<<dim3(HD / 128, 32, NE), 256, 0, stream>>>(
      midb, W2T, b2, counts, offsets, slot_token, (ushort_t*)nullptr, ybuf);
  combine_k<<<4096, 256, 0, stream>>>(ybuf, tk_e, tk_s, tk_w, offsets, out);
}

// Round 2
// 504.158 us; speedup vs baseline: 1.3064x; 1.3064x over previous
//
#include <hip/hip_runtime.h>

// MoE MLP (B=2,T=2048,H=1024,E=8,F=4096,K=2), fp32 in/out.
// route -> group tokens by expert -> grouped bf16-MFMA GEMMs (8-phase,
// counted-vmcnt, 256x256 tile, split-K=2 for GEMM2) -> weighted combine.

typedef unsigned short ushort_t;
typedef __attribute__((ext_vector_type(4))) unsigned int u32x4;
typedef __attribute__((ext_vector_type(4))) unsigned short u16x4;
typedef __attribute__((ext_vector_type(4))) float f32x4;
typedef __attribute__((ext_vector_type(8))) __bf16 bf16x8;

#define NTOK 4096   // B*T
#define HD   1024
#define FD   4096
#define NE   8
#define NKTOT 8192  // NTOK * TOP_K

__device__ __forceinline__ ushort_t f2bf(float f) {
  unsigned u = __builtin_bit_cast(unsigned, f);
  u += 0x7fffu + ((u >> 16) & 1u);   // RNE
  return (ushort_t)(u >> 16);
}

__device__ __forceinline__ bf16x8 frag_ld(const void* p) {
  u32x4 v = *reinterpret_cast<const u32x4*>(p);
  return __builtin_bit_cast(bf16x8, v);
}

#define GLOAD16(g, l) __builtin_amdgcn_global_load_lds(                         \
    (const __attribute__((address_space(1))) unsigned int*)(g),                 \
    (__attribute__((address_space(3))) unsigned int*)(l), 16, 0, 0)

#define WAITLGKM() do { asm volatile("s_waitcnt lgkmcnt(0)" ::: "memory");      \
                        __builtin_amdgcn_sched_barrier(0); } while (0)
#define WAITVM8() asm volatile("s_waitcnt vmcnt(8)" ::: "memory")
#define WAITVM4() asm volatile("s_waitcnt vmcnt(4)" ::: "memory")
#define WAITVM0() asm volatile("s_waitcnt vmcnt(0)" ::: "memory")

// ---------------------------------------------------------------- init
__global__ void init_k(int* counts) {
  if (threadIdx.x < NE) counts[threadIdx.x] = 0;
}

// ------------------------------------------------------- x fp32->bf16
__global__ void convx_k(const float* __restrict__ src, ushort_t* __restrict__ dst) {
  const size_t i = ((size_t)blockIdx.x * 256 + threadIdx.x) * 4;
  const f32x4 v = *reinterpret_cast<const f32x4*>(src + i);
  u16x4 o;
  o.x = f2bf(v.x); o.y = f2bf(v.y); o.z = f2bf(v.z); o.w = f2bf(v.w);
  *reinterpret_cast<u16x4*>(dst + i) = o;
}

// --------------------------- transpose+convert: src[z][R][C] -> dst[z][C][R]
__global__ void tconv_k(const float* __restrict__ src, ushort_t* __restrict__ dst,
                        int R, int C) {
  __shared__ float tile[64][65];
  const size_t zb = (size_t)blockIdx.z * R * C;
  const int r0 = blockIdx.y * 64, c0 = blockIdx.x * 64;
  const int tid = threadIdx.x;
  const int rl = tid >> 4, c4 = (tid & 15) * 4;
#pragma unroll
  for (int i = 0; i < 4; ++i) {
    const int r = rl + i * 16;
    const f32x4 v = *reinterpret_cast<const f32x4*>(src + zb + (size_t)(r0 + r) * C + c0 + c4);
    tile[r][c4 + 0] = v.x; tile[r][c4 + 1] = v.y;
    tile[r][c4 + 2] = v.z; tile[r][c4 + 3] = v.w;
  }
  __syncthreads();
  const int rr0 = (tid & 15) * 4, ccl = tid >> 4;
#pragma unroll
  for (int i = 0; i < 4; ++i) {
    const int cc = ccl + i * 16;
    u16x4 o;
    o.x = f2bf(tile[rr0 + 0][cc]); o.y = f2bf(tile[rr0 + 1][cc]);
    o.z = f2bf(tile[rr0 + 2][cc]); o.w = f2bf(tile[rr0 + 3][cc]);
    *reinterpret_cast<u16x4*>(dst + zb + (size_t)(c0 + cc) * R + r0 + rr0) = o;
  }
}

// ---------------------------------------------------------------- router
__global__ void router_k(const float* __restrict__ x, const float* __restrict__ rw,
                         float* __restrict__ tokP, int* __restrict__ counts,
                         int* __restrict__ tk_e, int* __restrict__ tk_s,
                         float* __restrict__ tk_w) {
  const int w = threadIdx.x >> 6, l = threadIdx.x & 63;
  const int t = blockIdx.x * 4 + w;
  const float* xr = x + (size_t)t * HD;
  float acc[NE];
#pragma unroll
  for (int e = 0; e < NE; ++e) acc[e] = 0.f;
  for (int it = 0; it < HD / 64; ++it) {
    const int h = l + it * 64;
    const float xv = xr[h];
#pragma unroll
    for (int e = 0; e < NE; ++e) acc[e] = fmaf(xv, rw[e * HD + h], acc[e]);
  }
#pragma unroll
  for (int e = 0; e < NE; ++e) {
#pragma unroll
    for (int s = 32; s > 0; s >>= 1) acc[e] += __shfl_xor(acc[e], s, 64);
  }
  float m = acc[0];
#pragma unroll
  for (int e = 1; e < NE; ++e) m = fmaxf(m, acc[e]);
  float ssum = 0.f;
  float p[NE];
#pragma unroll
  for (int e = 0; e < NE; ++e) { p[e] = expf(acc[e] - m); ssum += p[e]; }
  const float inv = 1.f / ssum;
  if (l < NE) tokP[(size_t)t * NE + l] = p[l] * inv;

  if (l == 0) {
    int i0 = 0; float v0 = acc[0];
#pragma unroll
    for (int e = 1; e < NE; ++e) if (acc[e] > v0) { v0 = acc[e]; i0 = e; }
    int i1 = -1; float v1 = -3.4e38f;
#pragma unroll
    for (int e = 0; e < NE; ++e) if (e != i0 && acc[e] > v1) { v1 = acc[e]; i1 = e; }
    const float w0 = 1.f / (1.f + expf(v1 - v0));
    const int s0 = atomicAdd(&counts[i0], 1);
    const int s1 = atomicAdd(&counts[i1], 1);
    tk_e[2 * t] = i0;     tk_s[2 * t] = s0;     tk_w[2 * t] = w0;
    tk_e[2 * t + 1] = i1; tk_s[2 * t + 1] = s1; tk_w[2 * t + 1] = 1.f - w0;
  }
}

// ------------------------------------------- offsets + aux loss + tail out
__global__ void finalize_k(const float* __restrict__ tokP, const int* __restrict__ counts,
                           int* __restrict__ offsets, float* __restrict__ out_tail) {
  __shared__ float red[16][8];
  const int tid = threadIdx.x;  // 1024
  f32x4 a0 = {0.f, 0.f, 0.f, 0.f}, a1 = {0.f, 0.f, 0.f, 0.f};
#pragma unroll
  for (int k = 0; k < 4; ++k) {
    const float* p = tokP + ((size_t)tid * 4 + k) * 8;
    a0 += *reinterpret_cast<const f32x4*>(p);
    a1 += *reinterpret_cast<const f32x4*>(p + 4);
  }
#pragma unroll
  for (int s = 1; s < 64; s <<= 1) {
#pragma unroll
    for (int c = 0; c < 4; ++c) {
      a0[c] += __shfl_xor(a0[c], s, 64);
      a1[c] += __shfl_xor(a1[c], s, 64);
    }
  }
  if ((tid & 63) == 0) {
    const int wv = tid >> 6;
#pragma unroll
    for (int c = 0; c < 4; ++c) { red[wv][c] = a0[c]; red[wv][4 + c] = a1[c]; }
  }
  __syncthreads();
  if (tid == 0) {
    float P[8];
    for (int c = 0; c < 8; ++c) {
      float s = 0.f;
      for (int q = 0; q < 16; ++q) s += red[q][c];
      P[c] = s * (1.f / NTOK);
    }
    int off = 0; float aux = 0.f;
    for (int q = 0; q < NE; ++q) { offsets[q] = off; off += counts[q]; }
    for (int q = 0; q < NE; ++q) aux += ((float)counts[q] / (float)NKTOT) * P[q];
    out_tail[0] = (float)NE * aux;
    out_tail[1] = 0.f;
  }
}

// ---------------------------------------------------------------- slots
__global__ void build_slots_k(const int* __restrict__ tk_e, const int* __restrict__ tk_s,
                              const int* __restrict__ offsets, int* __restrict__ slot_token) {
  const int i = blockIdx.x * 256 + threadIdx.x;  // < NKTOT
  const int e = tk_e[i];
  slot_token[offsets[e] + tk_s[i]] = i >> 1;
}

// ---------------- grouped GEMM, 256x256 tile, 8-phase counted-vmcnt schedule
// G1: mid[pos][FD] = gelu(X[tok] @ W1T[e]^T + b1[e])   A gathered, K=1024, NT=16
// G2: ybuf[half][pos][HD] = mid[pos][kslice] @ W2T[e][:,kslice]^T   split-K=2, NT=32
// LDS: [dbuf][A/B][kk-half][256 rows x 32 K elems], 128 KiB. Stage counter runs
// 6 half-tiles ahead; vmcnt(8) at q1/q3 phase ends keeps 4 halves in flight.
template <bool IS_G1>
__global__ __launch_bounds__(512) void moe_gemm8(
    const ushort_t* __restrict__ A, const ushort_t* __restrict__ Bm,
    const float* __restrict__ bias,
    const int* __restrict__ counts, const int* __restrict__ offsets,
    const int* __restrict__ slot_token,
    ushort_t* __restrict__ midout, float* __restrict__ ybuf) {
  constexpr int KD = IS_G1 ? HD : FD;
  constexpr int ND = IS_G1 ? FD : HD;
  constexpr int NT = IS_G1 ? 16 : 32;

  const int e    = IS_G1 ? blockIdx.z : (blockIdx.z >> 1);
  const int half = IS_G1 ? 0 : (blockIdx.z & 1);
  const int cnt = counts[e];
  const int ty = blockIdx.y;
  if (ty * 256 >= cnt) return;
  const int off = offsets[e];
  const int rows_rem = cnt - ty * 256;
  const int pos0 = off + ty * 256;
  const int n0 = blockIdx.x * 256;
  const int koff = half * 2048;   // elems into K

  __shared__ __align__(16) ushort_t lds[2][2][2][8192];

  const int tid = threadIdx.x;
  const int w = tid >> 6, l = tid & 63;
  const int wr = w >> 2, wc = w & 3;        // 2 (M) x 4 (N) waves

  // ---- staging source pointers (pre-swizzled): LDS(row, slot) holds global
  // k-chunk slot ^ xs(row), xs(row) = (row ^ (row>>2)) & 3.
  const int srow = l >> 2;                        // + c*128 + w*16
  const int xsl = ((l >> 2) ^ (l >> 4)) & 3;      // xs of this lane's staged rows
  const int sw  = (((l & 3) ^ xsl) << 4);         // source k-chunk byte in 64B row
  const char* asrc[2];
  const char* bsrc[2];
#pragma unroll
  for (int c = 0; c < 2; ++c) {
    const int ra = c * 128 + w * 16 + srow;
    int pos = pos0 + ra; if (pos > NKTOT - 1) pos = NKTOT - 1;  // masked at store
    const size_t arow = IS_G1 ? (size_t)slot_token[pos] : (size_t)pos;
    asrc[c] = (const char*)(A + arow * KD + koff) + sw;
    const int rb = n0 + c * 128 + w * 16 + srow;
    bsrc[c] = (const char*)(Bm + ((size_t)e * ND + rb) * KD + koff) + sw;
  }

  const int rslot = (l >> 4) ^ ((l ^ (l >> 2)) & 3);  // swizzled k-slot for frag reads

  auto STAGE = [&](int h) {
    if (h >= 4 * NT) return;
    const int t = h >> 2, ab = h & 1, kk = (h >> 1) & 1, b = t & 1;
    const int kb = t * 128 + kk * 64;               // byte offset into row
    ushort_t* d0 = &lds[b][ab][kk][w * 512];
    ushort_t* d1 = &lds[b][ab][kk][4096 + w * 512];
    GLOAD16((ab ? bsrc[0] : asrc[0]) + kb, d0);
    GLOAD16((ab ? bsrc[1] : asrc[1]) + kb, d1);
  };

  f32x4 acc[8][4] = {};

  auto LOADA = [&](bf16x8 (&af)[4], int b, int kk, int mq) {
#pragma unroll
    for (int mm = 0; mm < 4; ++mm) {
      const int row = wr * 128 + (mq * 4 + mm) * 16 + (l & 15);
      af[mm] = frag_ld(&lds[b][0][kk][row * 32 + rslot * 8]);
    }
  };
  auto LOADB = [&](bf16x8 (&bf)[4], int b, int kk) {
#pragma unroll
    for (int nn = 0; nn < 4; ++nn) {
      const int row = wc * 64 + nn * 16 + (l & 15);
      bf[nn] = frag_ld(&lds[b][1][kk][row * 32 + rslot * 8]);
    }
  };
  auto MF = [&](int mq, bf16x8 (&af)[4], bf16x8 (&bf)[4]) {
    __builtin_amdgcn_s_setprio(1);
#pragma unroll
    for (int mm = 0; mm < 4; ++mm)
#pragma unroll
      for (int nn = 0; nn < 4; ++nn)
        acc[mq * 4 + mm][nn] = __builtin_amdgcn_mfma_f32_16x16x32_bf16(
            af[mm], bf[nn], acc[mq * 4 + mm][nn], 0, 0, 0);
    __builtin_amdgcn_s_setprio(0);
  };

  // ---- prologue: prime 6 half-tiles (tile0 full + tile1 kk0)
#pragma unroll
  for (int h = 0; h < 6; ++h) STAGE(h);
  WAITVM8();                       // halves 0,1 (tile0 kk0) landed
  __builtin_amdgcn_s_barrier();

  bf16x8 af[4], bf[4];
  for (int t = 0; t < NT; ++t) {
    const int b = t & 1;
    // q0: A m0-3 kk0, B n0-3 kk0
    LOADA(af, b, 0, 0); LOADB(bf, b, 0);
    STAGE(4 * t + 6);              // A kk1 (t+1) -> other dbuf
    __builtin_amdgcn_s_barrier();
    WAITLGKM();
    MF(0, af, bf);
    __builtin_amdgcn_s_barrier();
    // q1: A m4-7 kk0 (B regs reused)
    LOADA(af, b, 0, 1);
    STAGE(4 * t + 7);              // B kk1 (t+1) -> other dbuf
    __builtin_amdgcn_s_barrier();
    WAITLGKM();
    MF(1, af, bf);
    if (t < NT - 1) { WAITVM8(); } else { WAITVM0(); }   // kk1(t) landed
    __builtin_amdgcn_s_barrier();
    // q2: A m0-3 kk1, B n0-3 kk1
    LOADA(af, b, 1, 0); LOADB(bf, b, 1);
    STAGE(4 * t + 8);              // A kk0 (t+2) -> this dbuf (last read was q1)
    __builtin_amdgcn_s_barrier();
    WAITLGKM();
    MF(0, af, bf);
    __builtin_amdgcn_s_barrier();
    // q3: A m4-7 kk1
    LOADA(af, b, 1, 1);
    STAGE(4 * t + 9);              // B kk0 (t+2) -> this dbuf (last read was q0)
    __builtin_amdgcn_s_barrier();
    WAITLGKM();
    MF(1, af, bf);
    if (t < NT - 2) { WAITVM8(); } else if (t == NT - 2) { WAITVM4(); }  // kk0(t+1)
    __builtin_amdgcn_s_barrier();
  }

  // ---- epilogue: C/D col = l&15, row = 4*(l>>4) + j
  float* yo = ybuf + (size_t)half * NKTOT * HD;
  const int lr4 = (l >> 4) * 4, lc = l & 15;
#pragma unroll
  for (int nn = 0; nn < 4; ++nn) {
    const int col = n0 + wc * 64 + nn * 16 + lc;
    const float bv = IS_G1 ? bias[(size_t)e * ND + col] : 0.f;
#pragma unroll
    for (int mm = 0; mm < 8; ++mm) {
      const int rbase = wr * 128 + mm * 16 + lr4;
#pragma unroll
      for (int j = 0; j < 4; ++j) {
        const int row = rbase + j;
        if (row < rows_rem) {
          float v = acc[mm][nn][j] + bv;
          if (IS_G1) {
            v = 0.5f * v * (1.0f + erff(v * 0.70710678118654752f));
            midout[(size_t)(pos0 + row) * FD + col] = f2bf(v);
          } else {
            yo[(size_t)(pos0 + row) * HD + col] = v;
          }
        }
      }
    }
  }
}

// ---------------------------------------------------------------- combine
__global__ void combine_k(const float* __restrict__ ybuf, const int* __restrict__ tk_e,
                          const int* __restrict__ tk_s, const float* __restrict__ tk_w,
                          const int* __restrict__ offsets, const float* __restrict__ b2,
                          float* __restrict__ out) {
  const int t = blockIdx.x;
  const int e0 = tk_e[2 * t], e1 = tk_e[2 * t + 1];
  const size_t p0 = (size_t)offsets[e0] + tk_s[2 * t];
  const size_t p1 = (size_t)offsets[e1] + tk_s[2 * t + 1];
  const float w0 = tk_w[2 * t], w1v = tk_w[2 * t + 1];
  const int h = threadIdx.x * 4;
  const size_t HALF = (size_t)NKTOT * HD;
  const f32x4 y0 = *reinterpret_cast<const f32x4*>(ybuf + p0 * HD + h)
                 + *reinterpret_cast<const f32x4*>(ybuf + HALF + p0 * HD + h)
                 + *reinterpret_cast<const f32x4*>(b2 + (size_t)e0 * HD + h);
  const f32x4 y1 = *reinterpret_cast<const f32x4*>(ybuf + p1 * HD + h)
                 + *reinterpret_cast<const f32x4*>(ybuf + HALF + p1 * HD + h)
                 + *reinterpret_cast<const f32x4*>(b2 + (size_t)e1 * HD + h);
  f32x4 o = y0 * w0 + y1 * w1v;
  *reinterpret_cast<f32x4*>(out + (size_t)t * HD + h) = o;
}

// ---------------------------------------------------------------- launch
extern "C" void kernel_launch(void* const* d_in, const int* in_sizes, int n_in,
                              void* d_out, int out_size, void* d_ws, size_t ws_size,
                              hipStream_t stream) {
  const float* x  = (const float*)d_in[0];
  const float* rw = (const float*)d_in[1];
  const float* w1 = (const float*)d_in[2];
  const float* b1 = (const float*)d_in[3];
  const float* w2 = (const float*)d_in[4];
  const float* b2 = (const float*)d_in[5];
  float* out = (float*)d_out;

  char* ws = (char*)d_ws;
  ushort_t* Xbf  = (ushort_t*)(ws + 0);            //  8,388,608
  ushort_t* W1T  = (ushort_t*)(ws + 8388608);      // 67,108,864  [E][F][H]
  ushort_t* W2T  = (ushort_t*)(ws + 75497472);     // 67,108,864  [E][H][F]
  ushort_t* midb = (ushort_t*)(ws + 142606336);    // 67,108,864  [NKTOT][F]
  float*    ybuf = (float*)(ws + 8388608);         // 67,108,864  [2][NKTOT][H], aliases W1T
  char* sm = ws + 209715200;
  int*   counts  = (int*)(sm);
  int*   offsets = (int*)(sm + 64);
  float* tokP    = (float*)(sm + 128);             // [NTOK][NE]
  int*   tk_e    = (int*)(sm + 128 + 131072);
  int*   tk_s    = (int*)(sm + 128 + 131072 + 32768);
  float* tk_w    = (float*)(sm + 128 + 131072 + 65536);
  int*   slot_token = (int*)(sm + 128 + 131072 + 98304);

  init_k<<<1, 64, 0, stream>>>(counts);
  convx_k<<<4096, 256, 0, stream>>>(x, Xbf);
  tconv_k<<<dim3(64, 16, 8), 256, 0, stream>>>(w1, W1T, HD, FD);  // [H][F]->[F][H]
  tconv_k<<<dim3(16, 64, 8), 256, 0, stream>>>(w2, W2T, FD, HD);  // [F][H]->[H][F]
  router_k<<<1024, 256, 0, stream>>>(x, rw, tokP, counts, tk_e, tk_s, tk_w);
  finalize_k<<<1, 1024, 0, stream>>>(tokP, counts, offsets, out + (size_t)NTOK * HD);
  build_slots_k<<<32, 256, 0, stream>>>(tk_e, tk_s, offsets, slot_token);
  moe_gemm8<true><<<dim3(16, 8, 8), 512, 0, stream>>>(
      Xbf, W1T, b1, counts, offsets, slot_token, midb, (float*)nullptr);
  moe_gemm8<false><<<dim3(4, 8, 16), 512, 0, stream>>>(
      midb, W2T, b2, counts, offsets, slot_token, (ushort_t*)nullptr, ybuf);
  combine_k<<<4096, 256, 0, stream>>>(ybuf, tk_e, tk_s, tk_w, offsets, b2, out);
}